// Round 12
// baseline (153.528 us; speedup 1.0000x reference)
//
#include <hip/hip_runtime.h>

// B=4, L=2048, H=8, E=D=64, float32, layout [b][l][h][e]. The
// LocalLogSymmetryMask allows per row i exactly columns j = i + D[c],
// 0 <= j < L, D = window -5..+5 plus +-(5+F), F(m)=(3^(m+1))>>(m+1)
// (monotone -> reference `break` == range check; edge branches == clipping).
// <= 47 candidates -> sparse attention.
//
// Round-12 (contiguity restructure): one 256-thread block per (b,i),
// covering ALL 8 heads. For fixed (b,j) the 8 heads' rows are one contiguous
// 2KB chunk -> every K/V load is a single contiguous 1KB wave-load (16
// sequential lines, one segment) instead of R8-R11's 4x256B gather segments.
// Wave w owns candidates c=12w..12w+11 (j wave-uniform -> all addresses
// scalar/SGPR, ~zero VALU address math). Dot butterfly amortized over 4
// heads (1 shfl per candidate-head vs 4 before). Scores -> LDS ps[48][8];
// every wave redundantly computes all-head softmax (lane = head*8+chunk,
// 6 candidates/lane, 3-level butterflies); PV fetches p via one ds_bpermute
// per stream; partials block-reduced through LDS; 1KB contiguous stores.
// Waves halve (32768 vs 65536); VALU ~0.5x; same FETCH (24.6 MB).

#define KB 4
#define KL 2048
#define KH 8
#define KE 64
#define KPB (KL * KH * KE)      // floats per batch = 1048576
#define KROW (KH * KE)          // floats per (b,j) all-head chunk = 512
#define KBLOCKS (KB * KL)       // 8192 blocks, one per (b,i)

// Candidate offsets: c 0..10 window (c-5); 11..28 left logs -(5+F);
// 29..46 right logs +(5+F); 47 dummy (always out of range).
static constexpr int kOff[48] = {
    -5, -4, -3, -2, -1, 0, 1, 2, 3, 4, 5,
    -6, -7, -8, -10, -12, -16, -22, -30, -43, -62, -91, -134, -199, -296,
    -442, -661, -990, -1482,
    6, 7, 8, 10, 12, 16, 22, 30, 43, 62, 91, 134, 199, 296, 442, 661, 990,
    1482,
    1 << 20};

__global__ __launch_bounds__(256)
void MaskAttention_20572893347881_kernel(
    const float* __restrict__ q, const float* __restrict__ k,
    const float* __restrict__ v, float* __restrict__ out) {
    __shared__ float ps[48][8];          // scores [candidate][head]
    __shared__ float accbuf[8][64][4];   // [wave*2+stream][lane][4]

    const int tid  = (int)threadIdx.x;
    const int lane = tid & 63;
    const int w    = __builtin_amdgcn_readfirstlane(tid >> 6);  // 0..3
    const int hh   = lane >> 4;          // head (stream 1) 0..3
    const int e4   = lane & 15;          // element-quad 0..15

    // XCD-locality swizzle over (b,i) blocks.
    const int pb = (int)blockIdx.x;
    const int lb = (pb & 7) * (KBLOCKS / 8) + (pb >> 3);
    const int i  = lb & (KL - 1);
    const int b  = lb >> 11;

    const float* __restrict__ kb   = k + (size_t)b * KPB;
    const float* __restrict__ vb   = v + (size_t)b * KPB;
    const float* __restrict__ qrow = q + (size_t)b * KPB + (size_t)i * KROW;
    float* __restrict__       orow = out + (size_t)b * KPB + (size_t)i * KROW;

    // Q for all 8 heads: two contiguous 1KB wave-loads; fold in 1/sqrt(64).
    float4 qf1 = *(const float4*)(qrow + lane * 4);
    float4 qf2 = *(const float4*)(qrow + KROW / 2 + lane * 4);
    qf1.x *= 0.125f; qf1.y *= 0.125f; qf1.z *= 0.125f; qf1.w *= 0.125f;
    qf2.x *= 0.125f; qf2.y *= 0.125f; qf2.z *= 0.125f; qf2.w *= 0.125f;

    // Wave w owns candidates c = 12w + t (all wave-uniform -> scalar).
    int  jr[12];
    bool okc[12];
#pragma unroll
    for (int t = 0; t < 12; ++t) {
        const int c  = 12 * w + t;
        const int ju = i + kOff[c];
        okc[t] = (ju >= 0) && (ju < KL);   // c==47 -> off=1<<20 -> false
        jr[t]  = okc[t] ? ju : 0;
    }

    // ---- Phase A: scores for 12 candidates x 8 heads ----
#pragma unroll
    for (int t = 0; t < 12; ++t) {
        const float* kr = kb + (size_t)jr[t] * KROW;
        const float4 k1 = *(const float4*)(kr + lane * 4);            // heads 0-3
        const float4 k2 = *(const float4*)(kr + KROW / 2 + lane * 4); // heads 4-7
        float d1 = qf1.x * k1.x + qf1.y * k1.y + qf1.z * k1.z + qf1.w * k1.w;
        float d2 = qf2.x * k2.x + qf2.y * k2.y + qf2.z * k2.z + qf2.w * k2.w;
        d1 += __shfl_xor(d1, 1, 64); d2 += __shfl_xor(d2, 1, 64);
        d1 += __shfl_xor(d1, 2, 64); d2 += __shfl_xor(d2, 2, 64);
        d1 += __shfl_xor(d1, 4, 64); d2 += __shfl_xor(d2, 4, 64);
        d1 += __shfl_xor(d1, 8, 64); d2 += __shfl_xor(d2, 8, 64);
        const float s1 = okc[t] ? d1 : -1e30f;
        const float s2 = okc[t] ? d2 : -1e30f;
        if (e4 == 0) {
            const int c = 12 * w + t;
            ps[c][hh]     = s1;
            ps[c][hh + 4] = s2;
        }
    }
    __syncthreads();

    // ---- Softmax (each wave redundantly, all 8 heads) ----
    // lane = (head sh = lane>>3, chunk ch = lane&7); chunk owns c = 6ch..6ch+5.
    const int sh = lane >> 3, ch = lane & 7;
    float pv[6];
    float mx = -1e30f;
#pragma unroll
    for (int u = 0; u < 6; ++u) {
        pv[u] = ps[ch * 6 + u][sh];
        mx = fmaxf(mx, pv[u]);
    }
    mx = fmaxf(mx, __shfl_xor(mx, 1, 64));
    mx = fmaxf(mx, __shfl_xor(mx, 2, 64));
    mx = fmaxf(mx, __shfl_xor(mx, 4, 64));
    float sum = 0.f;
#pragma unroll
    for (int u = 0; u < 6; ++u) {
        pv[u] = __expf(pv[u] - mx);   // invalid: -1e30 - mx -> exactly 0
        sum += pv[u];
    }
    sum += __shfl_xor(sum, 1, 64);
    sum += __shfl_xor(sum, 2, 64);
    sum += __shfl_xor(sum, 4, 64);
    const float inv = 1.f / sum;      // diagonal (c=5) always valid -> sum > 0
#pragma unroll
    for (int u = 0; u < 6; ++u) pv[u] *= inv;

    // ---- Phase C: PV for this wave's 12 candidates, all 8 heads ----
    float4 a1 = make_float4(0.f, 0.f, 0.f, 0.f);
    float4 a2 = make_float4(0.f, 0.f, 0.f, 0.f);
#pragma unroll
    for (int t = 0; t < 12; ++t) {
        const float* vr = vb + (size_t)jr[t] * KROW;
        const float4 v1 = *(const float4*)(vr + lane * 4);
        const float4 v2 = *(const float4*)(vr + KROW / 2 + lane * 4);
        // p[head][c], c = 12w+t lives in lane head*8 + (2w + t/6), reg t%6.
        const int chunk = 2 * w + (t >= 6 ? 1 : 0);
        const float p1 = __shfl(pv[t % 6], hh * 8 + chunk, 64);
        const float p2 = __shfl(pv[t % 6], (hh + 4) * 8 + chunk, 64);
        a1.x += p1 * v1.x; a1.y += p1 * v1.y; a1.z += p1 * v1.z; a1.w += p1 * v1.w;
        a2.x += p2 * v2.x; a2.y += p2 * v2.y; a2.z += p2 * v2.z; a2.w += p2 * v2.w;
    }
    *(float4*)(&accbuf[2 * w][lane][0])     = a1;
    *(float4*)(&accbuf[2 * w + 1][lane][0]) = a2;
    __syncthreads();

    // ---- Final cross-wave reduce + contiguous 1KB stores (waves 0,1) ----
    if (w < 2) {
        const float4 r0 = *(const float4*)(&accbuf[w][lane][0]);
        const float4 r1 = *(const float4*)(&accbuf[w + 2][lane][0]);
        const float4 r2 = *(const float4*)(&accbuf[w + 4][lane][0]);
        const float4 r3 = *(const float4*)(&accbuf[w + 6][lane][0]);
        float4 r;
        r.x = (r0.x + r1.x) + (r2.x + r3.x);
        r.y = (r0.y + r1.y) + (r2.y + r3.y);
        r.z = (r0.z + r1.z) + (r2.z + r3.z);
        r.w = (r0.w + r1.w) + (r2.w + r3.w);
        *(float4*)(orow + w * (KROW / 2) + lane * 4) = r;
    }
}

extern "C" void kernel_launch(void* const* d_in, const int* in_sizes, int n_in,
                              void* d_out, int out_size, void* d_ws, size_t ws_size,
                              hipStream_t stream) {
    (void)in_sizes; (void)n_in; (void)out_size; (void)d_ws; (void)ws_size;
    const float* q = (const float*)d_in[0];
    const float* k = (const float*)d_in[1];
    const float* v = (const float*)d_in[2];
    // d_in[3] (mask) unused: LocalLogSymmetryMask is a deterministic function
    // of L and is recomputed analytically in-kernel.
    float* out = (float*)d_out;

    hipLaunchKernelGGL(MaskAttention_20572893347881_kernel,
                       dim3(KBLOCKS), dim3(256), 0, stream,
                       q, k, v, out);
}